// Round 5
// baseline (422.399 us; speedup 1.0000x reference)
//
#include <hip/hip_runtime.h>
#include <hip/hip_bf16.h>
#include <stdint.h>

#define BATCH 4
#define SEQ 2048
#define DIM 1024
#define HEADS 16
#define HD 64
#define BH (BATCH*HEADS)
#define NQKV (3*DIM)

typedef __attribute__((ext_vector_type(8))) short bf16x8;
typedef __attribute__((ext_vector_type(4))) short bf16x4;
typedef __attribute__((ext_vector_type(4))) float f32x4;

#define MFMA16(a,b,c) __builtin_amdgcn_mfma_f32_16x16x32_bf16(a,b,c,0,0,0)

__device__ inline short f2bf(float f){
    __hip_bfloat16 h = __float2bfloat16(f);
    return *reinterpret_cast<short*>(&h);
}
__device__ inline float bf2f(short s){
    unsigned u = ((unsigned)(unsigned short)s) << 16;
    float f;
    __builtin_memcpy(&f, &u, 4);
    return f;
}

// ---------------- convert x -> bf16 ----------------
__global__ void conv_bf16(const float* __restrict__ in, short* __restrict__ out, int n){
    int i = blockIdx.x*blockDim.x + threadIdx.x;
    if (i < n) out[i] = f2bf(in[i]);
}

// ---------------- transpose + convert (R x C f32) -> (C x R bf16) ----------------
__global__ void transpose_conv(const float* __restrict__ in, short* __restrict__ out, int R, int C){
    __shared__ float tile[32][33];
    int c0 = blockIdx.x*32, r0 = blockIdx.y*32;
    int tx = threadIdx.x, ty = threadIdx.y;   // block (32,8)
    #pragma unroll
    for (int dy = 0; dy < 32; dy += 8)
        tile[ty+dy][tx] = in[(size_t)(r0+ty+dy)*C + c0+tx];
    __syncthreads();
    #pragma unroll
    for (int dy = 0; dy < 32; dy += 8)
        out[(size_t)(c0+ty+dy)*R + r0+tx] = f2bf(tile[tx][ty+dy]);
}

// ---------------- m97-style GEMM: C[MxN] = A[MxK] * Bt[NxK]^T ----------------
template<int WRITE_BF16>
__global__ void gemm_bt(const short* __restrict__ A, const short* __restrict__ Bt,
                        void* __restrict__ Cout, int M, int N, int K)
{
    __shared__ short As[128*32];
    __shared__ short Bs[128*32];
    const int t = threadIdx.x;
    const int lane = t & 63, wave = t >> 6;
    const int wr = wave >> 1, wc = wave & 1;      // 2x2 waves, each 64x64
    const int nbn = N >> 7;
    const int bm = blockIdx.x / nbn, bn = blockIdx.x % nbn;
    const int m0 = bm*128, n0 = bn*128;
    const int l15 = lane & 15, lhi = lane >> 4;

    f32x4 acc[4][4];
    #pragma unroll
    for (int i=0;i<4;i++)
        #pragma unroll
        for (int j=0;j<4;j++) acc[i][j] = (f32x4){0.f,0.f,0.f,0.f};

    for (int k0 = 0; k0 < K; k0 += 32) {
        #pragma unroll
        for (int it = 0; it < 2; ++it) {
            int base = (it*256 + wave*64)*8;      // wave-uniform elem offset into LDS tile
            int off  = base + lane*8;
            int row = off >> 5, col = off & 31;
            __builtin_amdgcn_global_load_lds(
                (const __attribute__((address_space(1))) void*)(A + (size_t)(m0+row)*K + k0 + col),
                (__attribute__((address_space(3))) void*)(As + base), 16, 0, 0);
            __builtin_amdgcn_global_load_lds(
                (const __attribute__((address_space(1))) void*)(Bt + (size_t)(n0+row)*K + k0 + col),
                (__attribute__((address_space(3))) void*)(Bs + base), 16, 0, 0);
        }
        __syncthreads();
        bf16x8 a[4], b[4];
        #pragma unroll
        for (int i=0;i<4;i++)
            a[i] = *(const bf16x8*)&As[(wr*64 + i*16 + l15)*32 + lhi*8];
        #pragma unroll
        for (int j=0;j<4;j++)
            b[j] = *(const bf16x8*)&Bs[(wc*64 + j*16 + l15)*32 + lhi*8];
        #pragma unroll
        for (int i=0;i<4;i++)
            #pragma unroll
            for (int j=0;j<4;j++)
                acc[i][j] = MFMA16(a[i], b[j], acc[i][j]);
        __syncthreads();
    }

    #pragma unroll
    for (int i=0;i<4;i++)
        #pragma unroll
        for (int j=0;j<4;j++)
            #pragma unroll
            for (int jj=0;jj<4;jj++) {
                int row = m0 + wr*64 + i*16 + lhi*4 + jj;
                int col = n0 + wc*64 + j*16 + l15;
                if (WRITE_BF16)
                    ((short*)Cout)[(size_t)row*N + col] = f2bf(acc[i][j][jj]);
                else
                    ((float*)Cout)[(size_t)row*N + col] = acc[i][j][jj];
            }
}

// ---------------- RoPE + scatter (all stores coalesced; V transposed via LDS) ----------------
__global__ __launch_bounds__(256) void rope_scatter(const short* __restrict__ qkvb,
                             short* __restrict__ qb, short* __restrict__ kb,
                             short* __restrict__ vtb,
                             float* __restrict__ kout, float* __restrict__ vout)
{
    __shared__ short vt[64*72];
    const int t = threadIdx.x;
    const int bh = blockIdx.x >> 5;
    const int sb = blockIdx.x & 31;
    const int b = bh >> 4, h = bh & 15;
    const int s_loc = t >> 2, ic = (t & 3) << 3;
    const int s = (sb << 6) + s_loc;
    const size_t rowbase = ((size_t)(b*SEQ + s))*NQKV + h*HD;

    bf16x8 q1 = *(const bf16x8*)&qkvb[rowbase + ic];
    bf16x8 q2 = *(const bf16x8*)&qkvb[rowbase + ic + 32];
    bf16x8 k1 = *(const bf16x8*)&qkvb[rowbase + DIM + ic];
    bf16x8 k2 = *(const bf16x8*)&qkvb[rowbase + DIM + ic + 32];
    bf16x8 v1 = *(const bf16x8*)&qkvb[rowbase + 2*DIM + ic];
    bf16x8 v2 = *(const bf16x8*)&qkvb[rowbase + 2*DIM + ic + 32];

    const float QS = 0.125f * 1.4426950408889634f;
    bf16x8 qo1, qo2, ko1, ko2;
    float k1f[8], k2f[8], v1f[8], v2f[8];
    #pragma unroll
    for (int j=0;j<8;j++){
        int i = ic + j;
        float inv = exp2f(-(float)i * (13.287712379549449f/32.0f));
        float ang = (float)s * inv;
        float sn, cs;
        sincosf(ang, &sn, &cs);
        float q1f = bf2f(q1[j]), q2f = bf2f(q2[j]);
        float ka = bf2f(k1[j]), kb_ = bf2f(k2[j]);
        float qr1 = q1f*cs - q2f*sn, qr2 = q2f*cs + q1f*sn;
        float kr1 = ka*cs - kb_*sn,  kr2 = kb_*cs + ka*sn;
        qo1[j] = f2bf(qr1*QS); qo2[j] = f2bf(qr2*QS);
        ko1[j] = f2bf(kr1);    ko2[j] = f2bf(kr2);
        k1f[j] = kr1; k2f[j] = kr2;
        v1f[j] = bf2f(v1[j]); v2f[j] = bf2f(v2[j]);
    }

    const size_t obase = ((size_t)bh*SEQ + s)*HD;
    *(bf16x8*)&qb[obase+ic]      = qo1;
    *(bf16x8*)&qb[obase+ic+32]   = qo2;
    *(bf16x8*)&kb[obase+ic]      = ko1;
    *(bf16x8*)&kb[obase+ic+32]   = ko2;
    #pragma unroll
    for (int j4=0;j4<2;j4++){
        *(f32x4*)&kout[obase+ic+j4*4]    = (f32x4){k1f[j4*4],k1f[j4*4+1],k1f[j4*4+2],k1f[j4*4+3]};
        *(f32x4*)&kout[obase+ic+32+j4*4] = (f32x4){k2f[j4*4],k2f[j4*4+1],k2f[j4*4+2],k2f[j4*4+3]};
        *(f32x4*)&vout[obase+ic+j4*4]    = (f32x4){v1f[j4*4],v1f[j4*4+1],v1f[j4*4+2],v1f[j4*4+3]};
        *(f32x4*)&vout[obase+ic+32+j4*4] = (f32x4){v2f[j4*4],v2f[j4*4+1],v2f[j4*4+2],v2f[j4*4+3]};
    }

    // stage V transposed: row i (0..63), 8 chunks of 8 s-elems, chunk-swizzled
    #pragma unroll
    for (int j=0;j<8;j++){
        int i = ic + j;
        vt[i*72 + ((((s_loc>>3) ^ (i&7) ^ (i>>3)) & 7)<<3) + (s_loc&7)] = v1[j];
        int i2 = i + 32;
        vt[i2*72 + ((((s_loc>>3) ^ (i2&7) ^ (i2>>3)) & 7)<<3) + (s_loc&7)] = v2[j];
    }
    __syncthreads();

    // phase 2: coalesced vtb store. i_out = t>>2, g = t&3 -> s chunk 2g, 2g+1
    const int i_out = t >> 2, g = t & 3;
    int c0 = 2*g, c1 = 2*g+1;
    bf16x8 r0 = *(const bf16x8*)&vt[i_out*72 + ((((c0) ^ (i_out&7) ^ (i_out>>3)) & 7)<<3)];
    bf16x8 r1 = *(const bf16x8*)&vt[i_out*72 + ((((c1) ^ (i_out&7) ^ (i_out>>3)) & 7)<<3)];
    size_t vrow = ((size_t)bh*HD + i_out)*SEQ + (sb<<6) + g*16;
    *(bf16x8*)&vtb[vrow]     = r0;
    *(bf16x8*)&vtb[vrow + 8] = r1;
}

// ---------------- flash attention ----------------
// 4 waves/block. Each PAIR of waves owns a 32-row q-tile; the two waves split its
// KV range in half (no-max softmax => partials combine by simple addition in LDS).
// Tiles paired (pp, 63-pp) so every wave runs ~33 kv32-steps. 4096 waves total.
#define PSTRIDE 40
#define CSTRIDE 35
__global__ __launch_bounds__(256, 4) void attn_kernel(
        const short* __restrict__ qb, const short* __restrict__ kb,
        const short* __restrict__ vtb, short* __restrict__ aob)
{
    __shared__ short Pl[4][32*PSTRIDE];
    __shared__ float comb[2][64*CSTRIDE];
    __shared__ float scl[2][32];

    const int t = threadIdx.x;
    const int lane = t & 63, wave = t >> 6;
    const int grp = wave >> 1, half = wave & 1;
    const int wg = blockIdx.x;               // 1024
    const int x = wg & 7, r = wg >> 3;       // XCD swizzle; r in 0..127
    const int bh = (x << 3) | (r >> 4);
    const int pp = ((r & 15) << 1) | grp;    // 0..31
    const int l15 = lane & 15, lhi = lane >> 4;
    const int b = bh >> 4, h = bh & 15;
    const size_t sbase = (size_t)bh * SEQ * HD;
    const short* vbase = vtb + (size_t)bh * HD * SEQ;
    short* pl = Pl[wave];

    #pragma unroll 1
    for (int part = 0; part < 2; ++part) {
        const int qt = part ? (63 - pp) : pp;
        const int q0 = qt << 5;
        const int n  = qt + 1;               // total kv32 steps for this tile
        const int mid = (n + 1) >> 1;
        const int lo = half ? mid : 0;
        const int hi = half ? n : mid;

        bf16x8 qf[2][2];
        #pragma unroll
        for (int f=0; f<2; f++)
            #pragma unroll
            for (int kk=0; kk<2; kk++)
                qf[f][kk] = *(const bf16x8*)&qb[sbase + (size_t)(q0 + f*16 + l15)*HD + kk*32 + lhi*8];

        f32x4 o[2][4];
        #pragma unroll
        for (int f=0; f<2; f++)
            #pragma unroll
            for (int d=0; d<4; d++) o[f][d] = (f32x4){0.f,0.f,0.f,0.f};
        float lsum[2] = {0.f, 0.f};

        bf16x8 kf[2][2];
        #pragma unroll
        for (int p=0;p<2;p++)
            #pragma unroll
            for (int kk=0;kk<2;kk++)
                kf[p][kk] = *(const bf16x8*)&kb[sbase + (size_t)(lo*32 + p*16 + l15)*HD + kk*32 + lhi*8];

        #pragma unroll 1
        for (int step = lo; step < hi; ++step) {
            const int kv0 = step << 5;

            bf16x8 kn[2][2];
            if (step + 1 < hi) {
                #pragma unroll
                for (int p=0;p<2;p++)
                    #pragma unroll
                    for (int kk=0;kk<2;kk++)
                        kn[p][kk] = *(const bf16x8*)&kb[sbase + (size_t)(kv0+32 + p*16 + l15)*HD + kk*32 + lhi*8];
            }
            bf16x8 vf[4];
            #pragma unroll
            for (int d=0;d<4;d++)
                vf[d] = *(const bf16x8*)&vbase[(size_t)(d*16 + l15)*SEQ + kv0 + lhi*8];

            // S^T[kv, q] = K . Q^T  (col=l15 -> q, row=lhi*4+jj -> kv)
            __builtin_amdgcn_s_setprio(1);
            f32x4 s[2][2];
            #pragma unroll
            for (int f=0;f<2;f++)
                #pragma unroll
                for (int p=0;p<2;p++){
                    s[f][p] = MFMA16(kf[p][0], qf[f][0], ((f32x4){0.f,0.f,0.f,0.f}));
                    s[f][p] = MFMA16(kf[p][1], qf[f][1], s[f][p]);
                }
            __builtin_amdgcn_s_setprio(0);

            if (step == n-1) {   // diagonal tile
                #pragma unroll
                for (int f=0;f<2;f++)
                    #pragma unroll
                    for (int p=0;p<2;p++)
                        #pragma unroll
                        for (int jj=0;jj<4;jj++){
                            int kv = kv0 + p*16 + lhi*4 + jj;
                            int q  = q0 + f*16 + l15;
                            if (kv > q) s[f][p][jj] = -3.0e38f;
                        }
            }

            // P = exp2(s); private partial row-sums (q = l15 + f*16)
            #pragma unroll
            for (int f=0;f<2;f++)
                #pragma unroll
                for (int p=0;p<2;p++){
                    bf16x4 pk;
                    #pragma unroll
                    for (int jj=0;jj<4;jj++){
                        float e = exp2f(s[f][p][jj]);
                        lsum[f] += e;
                        pk[jj] = f2bf(e);
                    }
                    *(bf16x4*)&pl[(f*16 + l15)*PSTRIDE + p*16 + lhi*4] = pk;
                }
            asm volatile("s_waitcnt lgkmcnt(0)" ::: "memory");
            __builtin_amdgcn_sched_barrier(0);

            bf16x8 pf[2];
            #pragma unroll
            for (int f=0;f<2;f++)
                pf[f] = *(const bf16x8*)&pl[(f*16 + l15)*PSTRIDE + lhi*8];
            __builtin_amdgcn_s_setprio(1);
            #pragma unroll
            for (int d=0;d<4;d++)
                #pragma unroll
                for (int f=0;f<2;f++)
                    o[f][d] = MFMA16(pf[f], vf[d], o[f][d]);
            __builtin_amdgcn_s_setprio(0);

            if (step + 1 < hi) {
                #pragma unroll
                for (int p=0;p<2;p++)
                    #pragma unroll
                    for (int kk=0;kk<2;kk++)
                        kf[p][kk] = kn[p][kk];
            }
        }

        // ---- combine the two kv-halves ----
        if (half == 0) {
            float* cb = &comb[grp][lane*CSTRIDE];
            #pragma unroll
            for (int f=0;f<2;f++)
                #pragma unroll
                for (int d=0;d<4;d++)
                    *(f32x4*)&cb[(f*4+d)*4] = o[f][d];
            cb[32] = lsum[0];
            cb[33] = lsum[1];
        }
        __syncthreads();
        if (half == 1) {
            const float* cb = &comb[grp][lane*CSTRIDE];
            #pragma unroll
            for (int f=0;f<2;f++)
                #pragma unroll
                for (int d=0;d<4;d++){
                    f32x4 c4 = *(const f32x4*)&cb[(f*4+d)*4];
                    #pragma unroll
                    for (int jj=0;jj<4;jj++) o[f][d][jj] += c4[jj];
                }
            lsum[0] += cb[32];
            lsum[1] += cb[33];
            #pragma unroll
            for (int f=0;f<2;f++){
                lsum[f] += __shfl_xor(lsum[f], 16);
                lsum[f] += __shfl_xor(lsum[f], 32);
            }
            if (lhi == 0) {
                scl[grp][l15]      = lsum[0];
                scl[grp][16 + l15] = lsum[1];
            }
            asm volatile("s_waitcnt lgkmcnt(0)" ::: "memory");
            __builtin_amdgcn_sched_barrier(0);

            #pragma unroll
            for (int f=0;f<2;f++){
                f32x4 l4 = *(const f32x4*)&scl[grp][f*16 + lhi*4];
                f32x4 inv4;
                #pragma unroll
                for (int jj=0;jj<4;jj++) inv4[jj] = 1.0f / l4[jj];
                #pragma unroll
                for (int d=0;d<4;d++)
                    #pragma unroll
                    for (int jj=0;jj<4;jj++){
                        int row = q0 + f*16 + lhi*4 + jj;
                        aob[((size_t)(b*SEQ + row))*DIM + h*HD + d*16 + l15] = f2bf(o[f][d][jj] * inv4[jj]);
                    }
            }
        }
        __syncthreads();   // protect comb/scl reuse across parts
    }
}

extern "C" void kernel_launch(void* const* d_in, const int* in_sizes, int n_in,
                              void* d_out, int out_size, void* d_ws, size_t ws_size,
                              hipStream_t stream) {
    const float* x     = (const float*)d_in[0];
    const float* w_qkv = (const float*)d_in[1];
    const float* w_out = (const float*)d_in[2];
    float* out  = (float*)d_out;
    float* kout = out + (size_t)BATCH*SEQ*DIM;          // 8388608
    float* vout = kout + (size_t)BH*SEQ*HD;             // +8388608

    char* ws = (char*)d_ws;
    short* xb    = (short*)(ws + 0);                    // 16 MB
    short* wqkvT = (short*)(ws + 16777216);             // 6 MB
    short* woutT = (short*)(ws + 23068672);             // 2 MB
    short* qkvb  = (short*)(ws + 25165824);             // 48 MB (8192x3072 bf16)
    short* qb    = (short*)(ws + 75497472);             // 16 MB
    short* kb    = (short*)(ws + 92274688);             // 16 MB
    short* vtb   = (short*)(ws + 109051904);            // 16 MB
    short* aob   = (short*)(ws + 125829120);            // 16 MB

    conv_bf16<<<(BATCH*SEQ*DIM)/256, 256, 0, stream>>>(x, xb, BATCH*SEQ*DIM);
    transpose_conv<<<dim3(NQKV/32, DIM/32), dim3(32,8), 0, stream>>>(w_qkv, wqkvT, DIM, NQKV);
    transpose_conv<<<dim3(DIM/32, DIM/32), dim3(32,8), 0, stream>>>(w_out, woutT, DIM, DIM);

    gemm_bt<1><<<(8192/128)*(NQKV/128), 256, 0, stream>>>(xb, wqkvT, qkvb, 8192, NQKV, DIM);

    rope_scatter<<<BH*(SEQ/64), 256, 0, stream>>>(qkvb, qb, kb, vtb, kout, vout);

    attn_kernel<<<1024, 256, 0, stream>>>(qb, kb, vtb, aob);

    gemm_bt<0><<<(8192/128)*(DIM/128), 256, 0, stream>>>(aob, woutT, out, 8192, DIM, DIM);
}

// Round 8
// 283.824 us; speedup vs baseline: 1.4882x; 1.4882x over previous
//
#include <hip/hip_runtime.h>
#include <hip/hip_bf16.h>
#include <stdint.h>

#define BATCH 4
#define SEQ 2048
#define DIM 1024
#define HEADS 16
#define HD 64
#define BH (BATCH*HEADS)
#define NQKV (3*DIM)

typedef __attribute__((ext_vector_type(8))) short bf16x8;
typedef __attribute__((ext_vector_type(4))) short bf16x4;
typedef __attribute__((ext_vector_type(4))) float f32x4;

#define MFMA16(a,b,c) __builtin_amdgcn_mfma_f32_16x16x32_bf16(a,b,c,0,0,0)

__device__ inline short f2bf(float f){
    __hip_bfloat16 h = __float2bfloat16(f);
    return *reinterpret_cast<short*>(&h);
}
__device__ inline float bf2f(short s){
    unsigned u = ((unsigned)(unsigned short)s) << 16;
    float f;
    __builtin_memcpy(&f, &u, 4);
    return f;
}

// ---------------- convert x -> bf16 ----------------
__global__ void conv_bf16(const float* __restrict__ in, short* __restrict__ out, int n){
    int i = blockIdx.x*blockDim.x + threadIdx.x;
    if (i < n) out[i] = f2bf(in[i]);
}

// ---------------- transpose + convert (R x C f32) -> (C x R bf16) ----------------
__global__ void transpose_conv(const float* __restrict__ in, short* __restrict__ out, int R, int C){
    __shared__ float tile[32][33];
    int c0 = blockIdx.x*32, r0 = blockIdx.y*32;
    int tx = threadIdx.x, ty = threadIdx.y;   // block (32,8)
    #pragma unroll
    for (int dy = 0; dy < 32; dy += 8)
        tile[ty+dy][tx] = in[(size_t)(r0+ty+dy)*C + c0+tx];
    __syncthreads();
    #pragma unroll
    for (int dy = 0; dy < 32; dy += 8)
        out[(size_t)(c0+ty+dy)*R + r0+tx] = f2bf(tile[tx][ty+dy]);
}

// ---------------- m97-style GEMM: C[MxN] = A[MxK] * Bt[NxK]^T ----------------
template<int WRITE_BF16>
__global__ void gemm_bt(const short* __restrict__ A, const short* __restrict__ Bt,
                        void* __restrict__ Cout, int M, int N, int K)
{
    __shared__ short As[128*32];
    __shared__ short Bs[128*32];
    const int t = threadIdx.x;
    const int lane = t & 63, wave = t >> 6;
    const int wr = wave >> 1, wc = wave & 1;      // 2x2 waves, each 64x64
    const int nbn = N >> 7;
    const int bm = blockIdx.x / nbn, bn = blockIdx.x % nbn;
    const int m0 = bm*128, n0 = bn*128;
    const int l15 = lane & 15, lhi = lane >> 4;

    f32x4 acc[4][4];
    #pragma unroll
    for (int i=0;i<4;i++)
        #pragma unroll
        for (int j=0;j<4;j++) acc[i][j] = (f32x4){0.f,0.f,0.f,0.f};

    for (int k0 = 0; k0 < K; k0 += 32) {
        #pragma unroll
        for (int it = 0; it < 2; ++it) {
            int base = (it*256 + wave*64)*8;      // wave-uniform elem offset into LDS tile
            int off  = base + lane*8;
            int row = off >> 5, col = off & 31;
            __builtin_amdgcn_global_load_lds(
                (const __attribute__((address_space(1))) void*)(A + (size_t)(m0+row)*K + k0 + col),
                (__attribute__((address_space(3))) void*)(As + base), 16, 0, 0);
            __builtin_amdgcn_global_load_lds(
                (const __attribute__((address_space(1))) void*)(Bt + (size_t)(n0+row)*K + k0 + col),
                (__attribute__((address_space(3))) void*)(Bs + base), 16, 0, 0);
        }
        __syncthreads();
        bf16x8 a[4], b[4];
        #pragma unroll
        for (int i=0;i<4;i++)
            a[i] = *(const bf16x8*)&As[(wr*64 + i*16 + l15)*32 + lhi*8];
        #pragma unroll
        for (int j=0;j<4;j++)
            b[j] = *(const bf16x8*)&Bs[(wc*64 + j*16 + l15)*32 + lhi*8];
        #pragma unroll
        for (int i=0;i<4;i++)
            #pragma unroll
            for (int j=0;j<4;j++)
                acc[i][j] = MFMA16(a[i], b[j], acc[i][j]);
        __syncthreads();
    }

    #pragma unroll
    for (int i=0;i<4;i++)
        #pragma unroll
        for (int j=0;j<4;j++)
            #pragma unroll
            for (int jj=0;jj<4;jj++) {
                int row = m0 + wr*64 + i*16 + lhi*4 + jj;
                int col = n0 + wc*64 + j*16 + l15;
                if (WRITE_BF16)
                    ((short*)Cout)[(size_t)row*N + col] = f2bf(acc[i][j][jj]);
                else
                    ((float*)Cout)[(size_t)row*N + col] = acc[i][j][jj];
            }
}

// ---------------- RoPE + scatter (all stores coalesced; V transposed via LDS) ----------------
__global__ __launch_bounds__(256) void rope_scatter(const short* __restrict__ qkvb,
                             short* __restrict__ qb, short* __restrict__ kb,
                             short* __restrict__ vtb,
                             float* __restrict__ kout, float* __restrict__ vout)
{
    __shared__ short vt[64*72];
    const int t = threadIdx.x;
    const int bh = blockIdx.x >> 5;
    const int sb = blockIdx.x & 31;
    const int b = bh >> 4, h = bh & 15;
    const int s_loc = t >> 2, ic = (t & 3) << 3;
    const int s = (sb << 6) + s_loc;
    const size_t rowbase = ((size_t)(b*SEQ + s))*NQKV + h*HD;

    bf16x8 q1 = *(const bf16x8*)&qkvb[rowbase + ic];
    bf16x8 q2 = *(const bf16x8*)&qkvb[rowbase + ic + 32];
    bf16x8 k1 = *(const bf16x8*)&qkvb[rowbase + DIM + ic];
    bf16x8 k2 = *(const bf16x8*)&qkvb[rowbase + DIM + ic + 32];
    bf16x8 v1 = *(const bf16x8*)&qkvb[rowbase + 2*DIM + ic];
    bf16x8 v2 = *(const bf16x8*)&qkvb[rowbase + 2*DIM + ic + 32];

    const float QS = 0.125f * 1.4426950408889634f;
    bf16x8 qo1, qo2, ko1, ko2;
    float k1f[8], k2f[8], v1f[8], v2f[8];
    #pragma unroll
    for (int j=0;j<8;j++){
        int i = ic + j;
        float inv = exp2f(-(float)i * (13.287712379549449f/32.0f));
        float ang = (float)s * inv;
        float sn, cs;
        sincosf(ang, &sn, &cs);
        float q1f = bf2f(q1[j]), q2f = bf2f(q2[j]);
        float ka = bf2f(k1[j]), kb_ = bf2f(k2[j]);
        float qr1 = q1f*cs - q2f*sn, qr2 = q2f*cs + q1f*sn;
        float kr1 = ka*cs - kb_*sn,  kr2 = kb_*cs + ka*sn;
        qo1[j] = f2bf(qr1*QS); qo2[j] = f2bf(qr2*QS);
        ko1[j] = f2bf(kr1);    ko2[j] = f2bf(kr2);
        k1f[j] = kr1; k2f[j] = kr2;
        v1f[j] = bf2f(v1[j]); v2f[j] = bf2f(v2[j]);
    }

    const size_t obase = ((size_t)bh*SEQ + s)*HD;
    *(bf16x8*)&qb[obase+ic]      = qo1;
    *(bf16x8*)&qb[obase+ic+32]   = qo2;
    *(bf16x8*)&kb[obase+ic]      = ko1;
    *(bf16x8*)&kb[obase+ic+32]   = ko2;
    #pragma unroll
    for (int j4=0;j4<2;j4++){
        *(f32x4*)&kout[obase+ic+j4*4]    = (f32x4){k1f[j4*4],k1f[j4*4+1],k1f[j4*4+2],k1f[j4*4+3]};
        *(f32x4*)&kout[obase+ic+32+j4*4] = (f32x4){k2f[j4*4],k2f[j4*4+1],k2f[j4*4+2],k2f[j4*4+3]};
        *(f32x4*)&vout[obase+ic+j4*4]    = (f32x4){v1f[j4*4],v1f[j4*4+1],v1f[j4*4+2],v1f[j4*4+3]};
        *(f32x4*)&vout[obase+ic+32+j4*4] = (f32x4){v2f[j4*4],v2f[j4*4+1],v2f[j4*4+2],v2f[j4*4+3]};
    }

    // stage V transposed: row i (0..63), 8 chunks of 8 s-elems, chunk-swizzled
    #pragma unroll
    for (int j=0;j<8;j++){
        int i = ic + j;
        vt[i*72 + ((((s_loc>>3) ^ (i&7) ^ (i>>3)) & 7)<<3) + (s_loc&7)] = v1[j];
        int i2 = i + 32;
        vt[i2*72 + ((((s_loc>>3) ^ (i2&7) ^ (i2>>3)) & 7)<<3) + (s_loc&7)] = v2[j];
    }
    __syncthreads();

    // phase 2: coalesced vtb store. i_out = t>>2, g = t&3 -> s chunk 2g, 2g+1
    const int i_out = t >> 2, g = t & 3;
    int c0 = 2*g, c1 = 2*g+1;
    bf16x8 r0 = *(const bf16x8*)&vt[i_out*72 + ((((c0) ^ (i_out&7) ^ (i_out>>3)) & 7)<<3)];
    bf16x8 r1 = *(const bf16x8*)&vt[i_out*72 + ((((c1) ^ (i_out&7) ^ (i_out>>3)) & 7)<<3)];
    size_t vrow = ((size_t)bh*HD + i_out)*SEQ + (sb<<6) + g*16;
    *(bf16x8*)&vtb[vrow]     = r0;
    *(bf16x8*)&vtb[vrow + 8] = r1;
}

// ---------------- flash attention, partial (KV-split across blocks) ----------------
// 1 wave/block, 32-row q-tile, no-max softmax (q pre-scaled by 0.125*log2e).
// Each (bh, qtile) split into two blocks (half=0: first ceil(n/2) kv steps,
// half=1: rest incl diagonal). Unnormalized partial O -> obuf (bf16),
// partial row-sums -> lbuf (f32). Tiles paired (pp, 63-pp): ~33 steps/block.
#define PSTRIDE 40
__global__ __launch_bounds__(64) void attn_partial(
        const short* __restrict__ qb, const short* __restrict__ kb,
        const short* __restrict__ vtb, short* __restrict__ obuf,
        float* __restrict__ lbuf)
{
    __shared__ short Pl[32*PSTRIDE];

    const int lane = threadIdx.x;
    const int wg = blockIdx.x;               // 4096 = 8x * 8bh-hi * 32pp * 2half
    const int x = wg & 7;                    // XCD swizzle
    const int r = wg >> 3;                   // 0..511
    const int half = r & 1;
    const int pp = (r >> 1) & 31;
    const int bh = (x << 3) | (r >> 6);
    const int l15 = lane & 15, lhi = lane >> 4;
    const size_t sbase = (size_t)bh * SEQ * HD;
    const short* vbase = vtb + (size_t)bh * HD * SEQ;

    #pragma unroll 1
    for (int part = 0; part < 2; ++part) {
        const int qt = part ? (63 - pp) : pp;
        const int q0 = qt << 5;
        const int n  = qt + 1;               // total kv32 steps for this tile
        const int mid = (n + 1) >> 1;
        const int lo = half ? mid : 0;
        const int hi = half ? n : mid;

        bf16x8 qf[2][2];
        #pragma unroll
        for (int f=0; f<2; f++)
            #pragma unroll
            for (int kk=0; kk<2; kk++)
                qf[f][kk] = *(const bf16x8*)&qb[sbase + (size_t)(q0 + f*16 + l15)*HD + kk*32 + lhi*8];

        f32x4 o[2][4];
        #pragma unroll
        for (int f=0; f<2; f++)
            #pragma unroll
            for (int d=0; d<4; d++) o[f][d] = (f32x4){0.f,0.f,0.f,0.f};
        float lsum[2] = {0.f, 0.f};

        bf16x8 kf[2][2];
        #pragma unroll
        for (int p=0;p<2;p++)
            #pragma unroll
            for (int kk=0;kk<2;kk++)
                kf[p][kk] = *(const bf16x8*)&kb[sbase + (size_t)(lo*32 + p*16 + l15)*HD + kk*32 + lhi*8];

        #pragma unroll 1
        for (int step = lo; step < hi; ++step) {
            const int kv0 = step << 5;

            bf16x8 kn[2][2];
            if (step + 1 < hi) {
                #pragma unroll
                for (int p=0;p<2;p++)
                    #pragma unroll
                    for (int kk=0;kk<2;kk++)
                        kn[p][kk] = *(const bf16x8*)&kb[sbase + (size_t)(kv0+32 + p*16 + l15)*HD + kk*32 + lhi*8];
            }
            bf16x8 vf[4];
            #pragma unroll
            for (int d=0;d<4;d++)
                vf[d] = *(const bf16x8*)&vbase[(size_t)(d*16 + l15)*SEQ + kv0 + lhi*8];

            // S^T[kv, q] = K . Q^T  (col=l15 -> q, row=lhi*4+jj -> kv)
            __builtin_amdgcn_s_setprio(1);
            f32x4 s[2][2];
            #pragma unroll
            for (int f=0;f<2;f++)
                #pragma unroll
                for (int p=0;p<2;p++){
                    s[f][p] = MFMA16(kf[p][0], qf[f][0], ((f32x4){0.f,0.f,0.f,0.f}));
                    s[f][p] = MFMA16(kf[p][1], qf[f][1], s[f][p]);
                }
            __builtin_amdgcn_s_setprio(0);

            if (step == n-1) {   // diagonal tile
                #pragma unroll
                for (int f=0;f<2;f++)
                    #pragma unroll
                    for (int p=0;p<2;p++)
                        #pragma unroll
                        for (int jj=0;jj<4;jj++){
                            int kv = kv0 + p*16 + lhi*4 + jj;
                            int q  = q0 + f*16 + l15;
                            if (kv > q) s[f][p][jj] = -3.0e38f;
                        }
            }

            // P = exp2(s); private partial row-sums (q = l15 + f*16)
            #pragma unroll
            for (int f=0;f<2;f++)
                #pragma unroll
                for (int p=0;p<2;p++){
                    bf16x4 pk;
                    #pragma unroll
                    for (int jj=0;jj<4;jj++){
                        float e = exp2f(s[f][p][jj]);
                        lsum[f] += e;
                        pk[jj] = f2bf(e);
                    }
                    *(bf16x4*)&Pl[(f*16 + l15)*PSTRIDE + p*16 + lhi*4] = pk;
                }
            asm volatile("s_waitcnt lgkmcnt(0)" ::: "memory");
            __builtin_amdgcn_sched_barrier(0);

            bf16x8 pf[2];
            #pragma unroll
            for (int f=0;f<2;f++)
                pf[f] = *(const bf16x8*)&Pl[(f*16 + l15)*PSTRIDE + lhi*8];
            __builtin_amdgcn_s_setprio(1);
            #pragma unroll
            for (int d=0;d<4;d++)
                #pragma unroll
                for (int f=0;f<2;f++)
                    o[f][d] = MFMA16(pf[f], vf[d], o[f][d]);
            __builtin_amdgcn_s_setprio(0);

            if (step + 1 < hi) {
                #pragma unroll
                for (int p=0;p<2;p++)
                    #pragma unroll
                    for (int kk=0;kk<2;kk++)
                        kf[p][kk] = kn[p][kk];
            }
        }

        // write unnormalized partial O (bf16) + partial row-sums (f32)
        short* ob = obuf + (size_t)(((bh << 6) | qt)*2 + half) * 2048;
        #pragma unroll
        for (int f=0;f<2;f++)
            #pragma unroll
            for (int d=0;d<4;d++)
                #pragma unroll
                for (int jj=0;jj<4;jj++)
                    ob[(f*16 + lhi*4 + jj)*64 + d*16 + l15] = f2bf(o[f][d][jj]);
        #pragma unroll
        for (int f=0;f<2;f++){
            lsum[f] += __shfl_xor(lsum[f], 16);
            lsum[f] += __shfl_xor(lsum[f], 32);
        }
        float* lb = lbuf + (size_t)(((bh << 6) | qt)*2 + half) * 32;
        if (lhi == 0) {
            lb[l15]      = lsum[0];
            lb[16 + l15] = lsum[1];
        }
    }
}

// ---------------- combine partials -> aob (bf16) ----------------
// grid 4096 = BH(64) * 64 q-tiles
__global__ __launch_bounds__(256) void attn_combine(const short* __restrict__ obuf,
                                                    const float* __restrict__ lbuf,
                                                    short* __restrict__ aob)
{
    const int t = threadIdx.x;
    const int tile = blockIdx.x;        // bh*64 + qt
    const int bh = tile >> 6, qt = tile & 63;
    const int b = bh >> 4, h = bh & 15;
    const int q0 = qt << 5;
    const short* o0 = obuf + (size_t)(tile*2) * 2048;
    const short* o1 = o0 + 2048;
    const float* lb = lbuf + (size_t)(tile*2) * 32;
    const int row = t >> 3, c0 = (t & 7) << 3;

    float inv = 1.0f / (lb[row] + lb[32 + row]);
    bf16x8 a = *(const bf16x8*)&o0[row*64 + c0];
    bf16x8 bq = *(const bf16x8*)&o1[row*64 + c0];
    bf16x8 ov;
    #pragma unroll
    for (int j=0;j<8;j++)
        ov[j] = f2bf((bf2f(a[j]) + bf2f(bq[j])) * inv);
    *(bf16x8*)&aob[((size_t)(b*SEQ + q0 + row))*DIM + h*HD + c0] = ov;
}

extern "C" void kernel_launch(void* const* d_in, const int* in_sizes, int n_in,
                              void* d_out, int out_size, void* d_ws, size_t ws_size,
                              hipStream_t stream) {
    const float* x     = (const float*)d_in[0];
    const float* w_qkv = (const float*)d_in[1];
    const float* w_out = (const float*)d_in[2];
    float* out  = (float*)d_out;
    float* kout = out + (size_t)BATCH*SEQ*DIM;          // 8388608
    float* vout = kout + (size_t)BH*SEQ*HD;             // +8388608

    char* ws = (char*)d_ws;
    short* xb    = (short*)(ws + 0);                    // 16 MB
    short* wqkvT = (short*)(ws + 16777216);             // 6 MB
    short* woutT = (short*)(ws + 23068672);             // 2 MB
    short* qkvb  = (short*)(ws + 25165824);             // 48 MB (8192x3072 bf16)
    // obuf/lbuf reuse the qkvb region (dead after rope_scatter):
    //   obuf: 4096 tiles * 2 halves * 2048 bf16 = 33.55 MB
    //   lbuf: 4096 * 2 * 32 f32 = 1.05 MB       -> total 34.6 MB < 48 MB
    short* obuf  = (short*)(ws + 25165824);
    float* lbuf  = (float*)(ws + 25165824 + 33554432);
    short* qb    = (short*)(ws + 75497472);             // 16 MB
    short* kb    = (short*)(ws + 92274688);             // 16 MB
    short* vtb   = (short*)(ws + 109051904);            // 16 MB
    short* aob   = (short*)(ws + 125829120);            // 16 MB

    conv_bf16<<<(BATCH*SEQ*DIM)/256, 256, 0, stream>>>(x, xb, BATCH*SEQ*DIM);
    transpose_conv<<<dim3(NQKV/32, DIM/32), dim3(32,8), 0, stream>>>(w_qkv, wqkvT, DIM, NQKV);
    transpose_conv<<<dim3(DIM/32, DIM/32), dim3(32,8), 0, stream>>>(w_out, woutT, DIM, DIM);

    gemm_bt<1><<<(8192/128)*(NQKV/128), 256, 0, stream>>>(xb, wqkvT, qkvb, 8192, NQKV, DIM);

    rope_scatter<<<BH*(SEQ/64), 256, 0, stream>>>(qkvb, qb, kb, vtb, kout, vout);

    attn_partial<<<4096, 64, 0, stream>>>(qb, kb, vtb, obuf, lbuf);
    attn_combine<<<4096, 256, 0, stream>>>(obuf, lbuf, aob);

    gemm_bt<0><<<(8192/128)*(DIM/128), 256, 0, stream>>>(aob, woutT, out, 8192, DIM, DIM);
}